// Round 1
// baseline (7988.605 us; speedup 1.0000x reference)
//
#include <hip/hip_runtime.h>
#include <math.h>

namespace {
constexpr int WSZ   = 7;
constexpr int HW    = 49;
constexpr int CIN   = 192;
constexpr int HEADS = 6;
constexpr int CH    = 32;   // CIN / HEADS
constexpr int IMG   = 224;

// One block per 7x7 window. 256 threads = 4 waves; lane = pixel (49 of 64 active),
// wave = row-group. Fully fused: QKV GEMM -> depthwise 3x3 -> normalized
// cross-cov attention -> softmax -> V*attn -> proj GEMM (register accum).
__global__ __launch_bounds__(256, 2)
void win_attn_fused(const float* __restrict__ x,
                    const float* __restrict__ w_qkv,
                    const float* __restrict__ b_qkv,
                    const float* __restrict__ w_dw,
                    const float* __restrict__ b_dw,
                    const float* __restrict__ w_proj,
                    const float* __restrict__ b_proj,
                    const float* __restrict__ temperature,
                    float* __restrict__ out)
{
    __shared__ float xs[48][HW];      //  9408 B: staged input-channel chunk
    __shared__ float qh[96][HW];      // 18816 B: this head's q(0-31)/k(32-63)/v(64-95)
    __shared__ float attnb[HW][50];   //  9800 B: 49x49 attn, padded stride
    __shared__ float outb[CH][HW];    //  6272 B: head attention output
    __shared__ float rnorm[2][HW];    //   392 B: 1/max(||q||,eps), 1/max(||k||,eps)

    const int tid  = threadIdx.x;
    const int lane = tid & 63;
    const int wv   = __builtin_amdgcn_readfirstlane(tid >> 6);  // wave id, uniform

    const int wi   = blockIdx.x;          // [0,4096)
    const int b    = wi >> 10;
    const int hy   = (wi >> 5) & 31;
    const int wx   = wi & 31;
    const int row0 = hy * WSZ, col0 = wx * WSZ;

    const int  p   = lane;                // pixel within window
    const bool act = (lane < HW);
    const int  py  = p / WSZ, px = p % WSZ;

    float pacc[48];                       // proj accumulator: oc = 48*wv + j
    #pragma unroll
    for (int j = 0; j < 48; ++j) pacc[j] = 0.f;

    for (int h = 0; h < HEADS; ++h) {
        // --- row -> qkv output-channel map for this wave (uniform) ---
        int oj[24];
        #pragma unroll
        for (int j = 0; j < 24; ++j) {
            int r = 24 * wv + j;          // [0,96): 0-31 q, 32-63 k, 64-95 v
            oj[j] = (r < 32) ? (CH * h + r)
                  : (r < 64) ? (CIN + CH * h + (r - 32))
                             : (2 * CIN + CH * h + (r - 64));
        }

        // --- Phase A: qkv_raw = W_qkv[oj] @ x_window ---
        float acc[24];
        #pragma unroll
        for (int j = 0; j < 24; ++j) acc[j] = 0.f;

        for (int cc0 = 0; cc0 < CIN; cc0 += 48) {
            for (int i = tid; i < 48 * HW; i += 256) {
                int c = i / HW, pp = i - c * HW;
                int gy = row0 + pp / WSZ, gx = col0 + pp % WSZ;
                xs[c][pp] = x[((b * CIN + (cc0 + c)) * IMG + gy) * IMG + gx];
            }
            __syncthreads();
            if (act) {
                #pragma unroll 4
                for (int c = 0; c < 48; ++c) {
                    float xv = xs[c][p];                 // 1 ds_read feeds 24 fma
                    #pragma unroll
                    for (int j = 0; j < 24; ++j)
                        acc[j] = fmaf(w_qkv[oj[j] * CIN + cc0 + c], xv, acc[j]);
                }
            }
            __syncthreads();
        }
        if (act) {
            #pragma unroll
            for (int j = 0; j < 24; ++j)
                qh[24 * wv + j][p] = acc[j] + b_qkv[oj[j]];
        }
        __syncthreads();

        // --- Phase B: depthwise 3x3, zero-padded within the 7x7 window ---
        float cv[24];
        if (act) {
            #pragma unroll
            for (int j = 0; j < 24; ++j) {
                int r = 24 * wv + j, o = oj[j];
                float s = b_dw[o];
                #pragma unroll
                for (int ky = 0; ky < 3; ++ky) {
                    int yy = py + ky - 1;
                    #pragma unroll
                    for (int kx = 0; kx < 3; ++kx) {
                        int xx = px + kx - 1;
                        bool ok = (yy >= 0) & (yy < WSZ) & (xx >= 0) & (xx < WSZ);
                        float v = ok ? qh[r][yy * WSZ + xx] : 0.f;
                        s = fmaf(w_dw[o * 9 + ky * 3 + kx], v, s);
                    }
                }
                cv[j] = s;
            }
        }
        __syncthreads();
        if (act) {
            #pragma unroll
            for (int j = 0; j < 24; ++j) qh[24 * wv + j][p] = cv[j];
        }
        __syncthreads();

        // --- Phase C: reciprocal L2 norms over the 32 channels, per pixel ---
        if (tid < 2 * HW) {
            int s  = (tid >= HW) ? 1 : 0;  // 0 = q, 1 = k
            int pp = tid - s * HW;
            float sum = 0.f;
            #pragma unroll
            for (int cc = 0; cc < CH; ++cc) {
                float v = qh[s * CH + cc][pp];
                sum = fmaf(v, v, sum);
            }
            rnorm[s][pp] = 1.0f / fmaxf(sqrtf(sum), 1e-12f);
        }
        __syncthreads();

        // --- Phase D: attn[n][m] = t * rk[n] * rq[m] * sum_c k[c][n] q[c][m] ---
        const float tmp = temperature[h];
        {
            int n0 = wv * 13;
            int n1 = (n0 + 13 < HW) ? (n0 + 13) : HW;
            if (act) {
                for (int n = n0; n < n1; ++n) {
                    float s = 0.f;
                    #pragma unroll
                    for (int cc = 0; cc < CH; ++cc)
                        s = fmaf(qh[CH + cc][n], qh[cc][p], s);  // broadcast * lane
                    attnb[n][p] = s * tmp * rnorm[1][n] * rnorm[0][p];
                }
            }
        }
        __syncthreads();

        // --- Phase E: softmax over n (keys), per column m ---
        if (tid < HW) {
            int m = tid;
            float mx = -1e30f;
            for (int n = 0; n < HW; ++n) mx = fmaxf(mx, attnb[n][m]);
            float sum = 0.f;
            for (int n = 0; n < HW; ++n) {
                float e = __expf(attnb[n][m] - mx);
                attnb[n][m] = e;
                sum += e;
            }
            float inv = 1.0f / sum;
            for (int n = 0; n < HW; ++n) attnb[n][m] *= inv;
        }
        __syncthreads();

        // --- Phase F: out[cc][m] = sum_n v[cc][n] * attn[n][m] ---
        if (act) {
            #pragma unroll
            for (int j = 0; j < 8; ++j) {
                int cc = 8 * wv + j;
                float s = 0.f;
                for (int n = 0; n < HW; ++n)
                    s = fmaf(qh[64 + cc][n], attnb[n][p], s);
                outb[cc][p] = s;
            }
        }
        __syncthreads();

        // --- Phase G: proj partial: pacc[oc] += W_proj[oc, 32h+cc] * out[cc] ---
        if (act) {
            for (int cc = 0; cc < CH; ++cc) {
                float ov = outb[cc][p];                  // 1 ds_read feeds 48 fma
                #pragma unroll
                for (int j = 0; j < 48; ++j)
                    pacc[j] = fmaf(w_proj[(48 * wv + j) * CIN + CH * h + cc], ov, pacc[j]);
            }
        }
        __syncthreads();
    }

    // --- epilogue: bias + window-reverse store ---
    if (act) {
        #pragma unroll
        for (int j = 0; j < 48; ++j) {
            int oc = 48 * wv + j;
            out[((b * CIN + oc) * IMG + row0 + py) * IMG + col0 + px] = pacc[j] + b_proj[oc];
        }
    }
}
} // namespace

extern "C" void kernel_launch(void* const* d_in, const int* in_sizes, int n_in,
                              void* d_out, int out_size, void* d_ws, size_t ws_size,
                              hipStream_t stream) {
    const float* x      = (const float*)d_in[0];
    const float* w_qkv  = (const float*)d_in[1];
    const float* b_qkv  = (const float*)d_in[2];
    const float* w_dw   = (const float*)d_in[3];
    const float* b_dw   = (const float*)d_in[4];
    const float* w_proj = (const float*)d_in[5];
    const float* b_proj = (const float*)d_in[6];
    const float* temp   = (const float*)d_in[7];

    win_attn_fused<<<dim3(4096), dim3(256), 0, stream>>>(
        x, w_qkv, b_qkv, w_dw, b_dw, w_proj, b_proj, temp, (float*)d_out);
}